// Round 3
// baseline (2488.190 us; speedup 1.0000x reference)
//
#include <hip/hip_runtime.h>
#include <stdint.h>

// CharRNN MI355X — XCD-local exchange, buffer_inv-refreshed flag barrier.
//   K1 k_prep : proj[v][h] = embedding[v,:] @ W_ih + b_h  (VOCAB=64 table)
//   K2 k_rnn  : persistent 256 blocks (1/CU). Block (gi,gj): batch rows
//               gi*32..+32, hidden cols gj*32..+32. W_hh slice bf16 in LDS.
//
//   Round-1/2 post-mortem: sc0 poll loads are served from the polling CU's
//   own L1; the poll loop pins the flag line hot -> frozen snapshot -> both
//   the r1 main barrier (3.3s of timeouts) and the r2 trial (fallback) died.
//   Data stayed correct because 64KB/step restage cycles the 32KB L1, so
//   ring lines are always evicted before reuse. Fix: poll = `buffer_inv sc0`
//   (vector-L1 flash invalidate, the gfx940+ acquire primitive) + plain load.
//
//   Three tiers, each trial-verified before engaging, one unanimous vote:
//     MODE 1: groups by physical XCD; plain stores/loads (local L2),
//             flag barrier w/ inv-refreshed polls.
//     MODE 2: agent-scope data path (verified), flag barrier at MALL
//             (parallel stores + coalesced poll; no serialized atomicAdd).
//     MODE 0: verified agent-scope fallback (round-0 2208us kernel).
//
// d_ws: proj f32 @0 (256KB) | cnt arena @262144 (8KB) | ring bf16 @1MB (16MB)
// cnt dwords: 0..255 mode0 counters | 256..511 per-XCD reg | 512 reg-total |
//   520 fail1 | 536 fail2 | 528 vote-total | 576..831 trial1 flags |
//   832..1087 trial2 flags | 1088..1343 main1 flags | 1344..1599 main2 flags

#define BATCH 256
#define SEQ   512
#define HID   1024
#define VOC   64
#define EMB   256
#define FINAL_OFF (BATCH * SEQ * VOC)   // 8388608
#define RING_SLOTS 32

typedef __attribute__((ext_vector_type(8))) short short8;
typedef __attribute__((ext_vector_type(4))) float f32x4;
typedef unsigned long long u64;

__device__ inline unsigned short f2bf(float f) {
  union { float f; unsigned u; } v; v.f = f;
  unsigned u = v.u;
  return (unsigned short)((u + 0x7FFFu + ((u >> 16) & 1u)) >> 16);  // RNE
}

// ---- agent-scope (MALL-point) ops — MODE 0/2 data path ---------------------
__device__ inline u64 cload64(const unsigned short* p) {
  return __hip_atomic_load((const u64*)p, __ATOMIC_RELAXED,
                           __HIP_MEMORY_SCOPE_AGENT);
}
__device__ inline void cstore32(unsigned short* p, unsigned v) {
  __hip_atomic_store((unsigned*)p, v, __ATOMIC_RELAXED,
                     __HIP_MEMORY_SCOPE_AGENT);
}

// ---------------- K1: projection table -------------------------------------
__global__ __launch_bounds__(256) void k_prep(const float* __restrict__ emb,
                                              const float* __restrict__ Wih,
                                              const float* __restrict__ bh,
                                              float* __restrict__ proj) {
  __shared__ float es[EMB];
  const int v = blockIdx.x >> 2;        // 0..63
  const int p = blockIdx.x & 3;         // h-quarter
  const int tid = threadIdx.x;
  es[tid] = emb[v * EMB + tid];
  __syncthreads();
  const int h = p * 256 + tid;
  float acc = bh[h];
  for (int e = 0; e < EMB; ++e) acc += es[e] * Wih[e * HID + h];
  proj[v * HID + h] = acc;
}

// ---------------- group barriers -------------------------------------------
// MODE 0: MALL-point atomic counter (verified 2208us path, unchanged).
__device__ inline void group_barrier(unsigned int* cnt_i, int tid, int round) {
  __syncthreads();
  if (tid == 0) {
    atomicAdd(cnt_i, 1u);
    int guard = 0;
    while (__hip_atomic_load(cnt_i, __ATOMIC_RELAXED, __HIP_MEMORY_SCOPE_AGENT)
           < 32u * (unsigned)round) {
      __builtin_amdgcn_s_sleep(1);
      if (++guard > (1 << 16)) break;    // bailout: wrong answer beats a hang
    }
  }
  __syncthreads();
}

// MODE 1: XCD-local flag barrier. Member m plain-stores `round` to its dword
// (dirty in local L2); wave0 lanes 0..31 poll with buffer_inv-sc0-refreshed
// plain loads (L1 flash invalidate -> load misses L1 -> fresh from L2).
// Release = __syncthreads' vmcnt(0) drain. Returns per-lane ok (wave0).
__device__ __forceinline__ int flag_barrier_l2(unsigned* __restrict__ barg,
                                               int m, unsigned round,
                                               int guard_max) {
  __syncthreads();                       // release: all waves' stores in L2
  int ok = 1;
  if (threadIdx.x < 64) {
    if (threadIdx.x == 0)
      asm volatile("global_store_dword %0, %1, off"
                   :: "v"(barg + m), "v"(round) : "memory");
    if (threadIdx.x < 32) {
      const unsigned* fp = barg + threadIdx.x;
      unsigned v; int g = 0;
      for (;;) {
        asm volatile("buffer_inv sc0" ::: "memory");   // flash-inv vector L1
        asm volatile("global_load_dword %0, %1, off\n\ts_waitcnt vmcnt(0)"
                     : "=v"(v) : "v"(fp) : "memory");
        if (v >= round) break;
        __builtin_amdgcn_s_sleep(1);
        if (++g > guard_max) { ok = 0; break; }
      }
    }
  }
  __syncthreads();                       // acquire for all waves
  return ok;
}

// MODE 2: flag barrier at the MALL — same coherence class as the verified
// agent data path (store visible to agent loads), but 32 parallel flag
// stores + one coalesced poll load instead of 32 serialized atomicAdds.
__device__ __forceinline__ int flag_barrier_mall(unsigned* __restrict__ barg,
                                                 int m, unsigned round,
                                                 int guard_max) {
  __syncthreads();
  int ok = 1;
  if (threadIdx.x < 64) {
    if (threadIdx.x == 0)
      __hip_atomic_store(barg + m, round, __ATOMIC_RELAXED,
                         __HIP_MEMORY_SCOPE_AGENT);
    if (threadIdx.x < 32) {
      int g = 0;
      while (__hip_atomic_load(barg + threadIdx.x, __ATOMIC_RELAXED,
                               __HIP_MEMORY_SCOPE_AGENT) < round) {
        __builtin_amdgcn_s_sleep(1);
        if (++g > guard_max) { ok = 0; break; }
      }
    }
  }
  __syncthreads();
  return ok;
}

// ---------------- K2 main loop (templated on coherence mode) ---------------
template <int MODE>
__device__ __forceinline__ void rnn_loop(
    const int* __restrict__ x, const float* __restrict__ Who,
    const float* __restrict__ bo, unsigned short* __restrict__ ring,
    float* __restrict__ out, float* __restrict__ final_out,
    unsigned int* __restrict__ cnt, const int gi, const int gj,
    unsigned short* w_lds, char* h_lds, float* p_lds, int* xs) {
  const int tid = threadIdx.x;
  const int row0 = gi * 32;
  const int lane = tid & 63, wv = tid >> 6;
  const int mt = wv & 1, nt = wv >> 1;                      // recurrence tiles
  const int l15 = lane & 15, q = lane >> 4;

  // W_ho B-fragments for this wave's 16-voc tile (compiler may rematerialize).
  short8 wf[32];
  #pragma unroll
  for (int kb = 0; kb < 32; ++kb) {
    short8 v8;
    #pragma unroll
    for (int j = 0; j < 8; ++j)
      v8[j] = (short)f2bf(Who[(kb * 32 + q * 8 + j) * VOC + wv * 16 + l15]);
    wf[kb] = v8;
  }

  unsigned int* cnt_i = cnt + gi * 32;                      // mode0 counter
  unsigned int* barg1 = cnt + 1088 + gi * 32;               // mode1 flags
  unsigned int* barg2 = cnt + 1344 + gi * 32;               // mode2 flags
  const int hcol = gj * 32 + nt * 16 + l15;
  const char* abase = h_lds + (mt * 16 + l15) * 2064 + q * 16;
  const char* bbase = (const char*)w_lds + (q * 32 + nt * 16 + l15) * 16;
  const float bias = bo[wv * 16 + l15];

  for (int t = 0; t < SEQ; ++t) {
    // 1) recurrence MFMA: 32x32 tile = h_prev(32x1024) @ Whh_slice(1024x32)
    f32x4 a0 = {0.f, 0.f, 0.f, 0.f}, a1 = {0.f, 0.f, 0.f, 0.f};
    if (t > 0) {
      #pragma unroll 4
      for (int kb = 0; kb < 32; kb += 2) {
        short8 af0 = *(const short8*)(abase + kb * 64);
        short8 bf0 = *(const short8*)(bbase + kb * 2048);
        a0 = __builtin_amdgcn_mfma_f32_16x16x32_bf16(af0, bf0, a0, 0, 0, 0);
        short8 af1 = *(const short8*)(abase + kb * 64 + 64);
        short8 bf1 = *(const short8*)(bbase + kb * 2048 + 2048);
        a1 = __builtin_amdgcn_mfma_f32_16x16x32_bf16(af1, bf1, a1, 0, 0, 0);
      }
    }
    // 2) epilogue: h_t = tanh(proj[x_t] + acc); publish packed col-pairs.
    unsigned short* slot = ring + (size_t)(t & (RING_SLOTS - 1)) * (BATCH * HID);
    float hv[4];
    #pragma unroll
    for (int r = 0; r < 4; ++r) {
      int ml = mt * 16 + q * 4 + r;                         // D row = q*4+r
      hv[r] = tanhf(p_lds[xs[ml] * 32 + nt * 16 + l15] + a0[r] + a1[r]);
      if (t == SEQ - 1) final_out[(row0 + ml) * HID + hcol] = hv[r];
    }
    #pragma unroll
    for (int r = 0; r < 4; ++r) {
      unsigned myb = f2bf(hv[r]);
      unsigned oth = (unsigned)__shfl_xor((int)myb, 1);
      if ((l15 & 1) == 0) {
        int b = row0 + mt * 16 + q * 4 + r;
        unsigned pk2 = myb | (oth << 16);
        if (MODE == 1)
          *(unsigned*)(slot + (size_t)b * HID + hcol) = pk2;  // dirty in L2
        else
          cstore32(slot + (size_t)b * HID + hcol, pk2);
      }
    }
    // 3) group barrier
    if (MODE == 1)      flag_barrier_l2(barg1, gj, (unsigned)(t + 1), 1 << 12);
    else if (MODE == 2) flag_barrier_mall(barg2, gj, (unsigned)(t + 1), 1 << 14);
    else                group_barrier(cnt_i, tid, t + 1);
    // 4) chunked logits every 16 steps: this block does 16 rows x 1 t x 64 v
    if ((t & 15) == 15) {
      int tsel  = (t - 15) + (gj >> 1);
      int rbase = row0 + (gj & 1) * 16;
      const unsigned short* hs =
          ring + (size_t)(tsel & (RING_SLOTS - 1)) * (BATCH * HID) +
          (size_t)(rbase + l15) * HID;                      // A row base
      f32x4 lc = {0.f, 0.f, 0.f, 0.f};
      for (int g = 0; g < 4; ++g) {
        u64 hb[16];
        #pragma unroll
        for (int j = 0; j < 8; ++j) {
          const unsigned short* pk = hs + (g * 8 + j) * 32 + q * 8;
          if (MODE == 1) {                 // L1 inv'd during barrier polls
            hb[2 * j]     = *(const u64*)pk;
            hb[2 * j + 1] = *(const u64*)(pk + 4);
          } else {
            hb[2 * j]     = cload64(pk);
            hb[2 * j + 1] = cload64(pk + 4);
          }
        }
        #pragma unroll
        for (int j = 0; j < 8; ++j) {
          union { u64 d[2]; short8 s; } c;
          c.d[0] = hb[2 * j]; c.d[1] = hb[2 * j + 1];
          lc = __builtin_amdgcn_mfma_f32_16x16x32_bf16(c.s, wf[g * 8 + j],
                                                       lc, 0, 0, 0);
        }
      }
      #pragma unroll
      for (int rr = 0; rr < 4; ++rr) {
        int b = rbase + q * 4 + rr;
        out[((size_t)b * SEQ + tsel) * VOC + wv * 16 + l15] = lc[rr] + bias;
      }
      // no reuse barrier needed: 32-slot ring, reuse is >=16 barriers away
    }
    // 5) restage h_t (32 rows x 1024) -> h_lds
    if (t < SEQ - 1) {
      u64 tmp[32];
      const unsigned short* base = slot + (size_t)row0 * HID + tid * 4;
      #pragma unroll
      for (int rr = 0; rr < 32; ++rr) {
        if (MODE == 1) tmp[rr] = *(const u64*)(base + (size_t)rr * HID);
        else           tmp[rr] = cload64(base + (size_t)rr * HID);
      }
      #pragma unroll
      for (int rr = 0; rr < 32; ++rr)
        *(u64*)(h_lds + rr * 2064 + tid * 8) = tmp[rr];
      if (tid < 32) xs[tid] = x[(row0 + tid) * SEQ + (t + 1)];
      __syncthreads();
    }
  }
}

// ---------------- K2: persistent recurrence + inline logits ----------------
// LDS: w_lds 65536 | h_lds 66048 (32 rows x 2064B) | p_lds 8192 | xs 128
__global__ __launch_bounds__(256, 1) void k_rnn(
    const int* __restrict__ x, const float* __restrict__ Whh,
    const float* __restrict__ proj, const float* __restrict__ Who,
    const float* __restrict__ bo, unsigned short* __restrict__ ring,
    float* __restrict__ out, float* __restrict__ final_out,
    unsigned int* __restrict__ cnt) {
  extern __shared__ char smem[];
  unsigned short* w_lds = (unsigned short*)smem;            // 65536
  char*           h_lds = smem + 65536;                     // 66048
  float*          p_lds = (float*)(smem + 131584);          // 8192
  int*            xs    = (int*)(smem + 139776);            // 128

  const int tid = threadIdx.x, bid = blockIdx.x;

  // --- Phase A: XCD registration (device-scope atomics at MALL) ------------
  if (tid == 0) {
    unsigned xcc;
    asm volatile("s_getreg_b32 %0, hwreg(HW_REG_XCC_ID)" : "=s"(xcc));
    xcc &= 7u;
    unsigned* xreg = cnt + 256;
    unsigned* xtot = cnt + 512;
    unsigned m = atomicAdd(xreg + xcc * 32, 1u);
    atomicAdd(xtot, 1u);
    unsigned tot = 0; int guard = 0;
    do {
      tot = __hip_atomic_load(xtot, __ATOMIC_RELAXED, __HIP_MEMORY_SCOPE_AGENT);
      if (tot >= 256u) break;
      __builtin_amdgcn_s_sleep(2);
    } while (++guard < (1 << 16));
    int ok = (tot >= 256u) && (m < 32u);
    for (int i = 0; i < 8; ++i)
      ok &= (__hip_atomic_load(xreg + i * 32, __ATOMIC_RELAXED,
                               __HIP_MEMORY_SCOPE_AGENT) == 32u);
    xs[0] = ok;
    xs[1] = (int)xcc;
    xs[2] = (int)m;
  }
  __syncthreads();
  const int regok = xs[0];
  const int gi_f  = xs[1], gj_f = xs[2];   // candidate mode-1 assignment
  __syncthreads();

  // --- Phase B: trials (self-tests, bounded guards) ------------------------
  int fast1 = regok;
  if (regok) {                             // uniform branch (regok from MALL)
    unsigned* tr1 = cnt + 576 + gi_f * 32;
    for (int r = 1; r <= 2; ++r) {
      int t1 = flag_barrier_l2(tr1, gj_f, (unsigned)r, 2048);
      if (tid < 64) fast1 = fast1 && __all(t1);
    }
  }
  int fast2 = 1;                           // MALL flags, bid-based groups
  {
    unsigned* tr2 = cnt + 832 + (bid & 7) * 32;
    for (int r = 1; r <= 2; ++r) {
      int t2 = flag_barrier_mall(tr2, bid >> 3, (unsigned)r, 8192);
      if (tid < 64) fast2 = fast2 && __all(t2);
    }
  }

  // --- Phase C: unanimous vote (device-scope, MALL) ------------------------
  if (tid == 0) {
    if (!fast1) atomicAdd(cnt + 520, 1u);
    if (!fast2) atomicAdd(cnt + 536, 1u);
    asm volatile("s_waitcnt vmcnt(0)" ::: "memory");  // fail-adds before total
    atomicAdd(cnt + 528, 1u);
    unsigned vt = 0; int guard = 0;
    do {
      vt = __hip_atomic_load(cnt + 528, __ATOMIC_RELAXED,
                             __HIP_MEMORY_SCOPE_AGENT);
      if (vt >= 256u) break;
      __builtin_amdgcn_s_sleep(2);
    } while (++guard < (1 << 16));
    unsigned f1 = __hip_atomic_load(cnt + 520, __ATOMIC_RELAXED,
                                    __HIP_MEMORY_SCOPE_AGENT);
    unsigned f2 = __hip_atomic_load(cnt + 536, __ATOMIC_RELAXED,
                                    __HIP_MEMORY_SCOPE_AGENT);
    int mode = 0;
    if (vt >= 256u) mode = (f1 == 0u) ? 1 : ((f2 == 0u) ? 2 : 0);
    xs[0] = mode;
    xs[1] = (mode == 1) ? gi_f : (bid & 7);
    xs[2] = (mode == 1) ? gj_f : (bid >> 3);
  }
  __syncthreads();
  const int mode = xs[0];
  const int gi = xs[1], gj = xs[2];                         // group / col-slice
  __syncthreads();

  // W_hh column slice -> LDS bf16 B-fragment order (once).
  for (int it = 0; it < 128; ++it) {
    int u = it * 256 + tid;
    int n = u & 31, j8 = (u >> 5) & 7, qq = (u >> 8) & 3, kb = u >> 10;
    w_lds[((kb * 4 + qq) * 32 + n) * 8 + j8] =
        f2bf(Whh[(kb * 32 + qq * 8 + j8) * HID + gj * 32 + n]);
  }
  // proj slice [64 vocab][32 cols] -> LDS f32 (once).
  for (int it = 0; it < 8; ++it) {
    int u = it * 256 + tid;
    p_lds[u] = proj[(u >> 5) * HID + gj * 32 + (u & 31)];
  }
  if (tid < 32) xs[tid] = x[(gi * 32 + tid) * SEQ];
  __syncthreads();

  if (mode == 1)
    rnn_loop<1>(x, Who, bo, ring, out, final_out, cnt, gi, gj,
                w_lds, h_lds, p_lds, xs);
  else if (mode == 2)
    rnn_loop<2>(x, Who, bo, ring, out, final_out, cnt, gi, gj,
                w_lds, h_lds, p_lds, xs);
  else
    rnn_loop<0>(x, Who, bo, ring, out, final_out, cnt, gi, gj,
                w_lds, h_lds, p_lds, xs);
}

// ---------------- launch ----------------------------------------------------
extern "C" void kernel_launch(void* const* d_in, const int* in_sizes, int n_in,
                              void* d_out, int out_size, void* d_ws, size_t ws_size,
                              hipStream_t stream) {
  const int*   x   = (const int*)d_in[0];
  const float* emb = (const float*)d_in[1];
  const float* Wih = (const float*)d_in[2];
  const float* Whh = (const float*)d_in[3];
  const float* bh  = (const float*)d_in[4];
  const float* Who = (const float*)d_in[5];
  const float* bo  = (const float*)d_in[6];
  float* out = (float*)d_out;

  char* ws = (char*)d_ws;
  float*          proj = (float*)ws;                         // 262144 B
  unsigned int*   cnt  = (unsigned int*)(ws + 262144);       // 8192 B
  unsigned short* ring = (unsigned short*)(ws + (1 << 20));  // 16 MiB

  size_t need = (size_t)(1 << 20) + (size_t)RING_SLOTS * BATCH * HID * 2;
  if (ws_size < need) return;  // diagnostic fail (absmax) instead of a fault

  (void)hipFuncSetAttribute(reinterpret_cast<const void*>(k_rnn),
                            hipFuncAttributeMaxDynamicSharedMemorySize, 139904);

  k_prep<<<256, 256, 0, stream>>>(emb, Wih, bh, proj);
  hipMemsetAsync(cnt, 0, 8192, stream);
  k_rnn<<<256, 256, 139904, stream>>>(x, Whh, proj, Who, bo, ring,
                                      out, out + FINAL_OFF, cnt);
}

// Round 4
// 2270.626 us; speedup vs baseline: 1.0958x; 1.0958x over previous
//
#include <hip/hip_runtime.h>
#include <stdint.h>

// CharRNN MI355X — per-producer flag exchange, barrier-free edition.
//   K1 k_prep : proj[v][h] = embedding[v,:] @ W_ih + b_h  (VOCAB=64 table)
//   K2 k_rnn  : persistent 256 blocks (1/CU). Block (gi,gj): batch rows
//               gi*32..+32, hidden cols gj*32..+32. W_hh slice bf16 in LDS.
//
//   Round 1-3 post-mortem: XCD-local (L2-point) exchange is unreachable from
//   HIP on this part (3 distinct poll/inv schemes all froze); and a parallel
//   flag barrier in ONE 128B line matched the serialized-atomicAdd barrier
//   (stores from 32 blocks to the same MALL line serialize the same way).
//   So: stay on the PROVEN agent-scope (MALL) coherence class, and instead
//   restructure the synchronization:
//     - 32 per-producer flags per group, each flag in its OWN 128B line
//       (no same-line store serialization, no dedicated barrier round-trip).
//     - producer release = data stores -> __syncthreads() (vmcnt(0) drain,
//       the round-0-proven idiom) -> one agent flag store.
//     - restage is producer-granular: thread tid reads cols tid*4..+3, which
//       belong to exactly one producer (tid>>3); it waits on THAT flag only,
//       so chunks stream in as producers arrive. Only remaining block-wide
//       wait is the LDS __syncthreads().
//     - logits (every 16 steps) wait-all on slot tsel (binding only for
//       tsel==t; skew bound makes older slots free).
//   No registration / trials / votes — single variant.
//
// d_ws: proj f32 @0 (256KB) | flags @262144 (32KB: 8 grp x 32 prod x 128B)
//       | ring bf16 @1MB (16MB)

#define BATCH 256
#define SEQ   512
#define HID   1024
#define VOC   64
#define EMB   256
#define FINAL_OFF (BATCH * SEQ * VOC)   // 8388608
#define RING_SLOTS 32

typedef __attribute__((ext_vector_type(8))) short short8;
typedef __attribute__((ext_vector_type(4))) float f32x4;
typedef unsigned long long u64;

__device__ inline unsigned short f2bf(float f) {
  union { float f; unsigned u; } v; v.f = f;
  unsigned u = v.u;
  return (unsigned short)((u + 0x7FFFu + ((u >> 16) & 1u)) >> 16);  // RNE
}

// ---- agent-scope (MALL-point) ops — the PROVEN coherence class -------------
__device__ inline u64 cload64(const unsigned short* p) {
  return __hip_atomic_load((const u64*)p, __ATOMIC_RELAXED,
                           __HIP_MEMORY_SCOPE_AGENT);
}
__device__ inline void cstore32(unsigned short* p, unsigned v) {
  __hip_atomic_store((unsigned*)p, v, __ATOMIC_RELAXED,
                     __HIP_MEMORY_SCOPE_AGENT);
}

// poll one flag until >= target (agent relaxed load, proven in round-0 poll)
__device__ __forceinline__ void wait_flag(const unsigned* __restrict__ f,
                                          unsigned target) {
  int g = 0;
  while (__hip_atomic_load(f, __ATOMIC_RELAXED, __HIP_MEMORY_SCOPE_AGENT)
         < target) {
    __builtin_amdgcn_s_sleep(1);
    if (++g > (1 << 16)) break;          // bailout: wrong answer beats a hang
  }
}

// ---------------- K1: projection table -------------------------------------
__global__ __launch_bounds__(256) void k_prep(const float* __restrict__ emb,
                                              const float* __restrict__ Wih,
                                              const float* __restrict__ bh,
                                              float* __restrict__ proj) {
  __shared__ float es[EMB];
  const int v = blockIdx.x >> 2;        // 0..63
  const int p = blockIdx.x & 3;         // h-quarter
  const int tid = threadIdx.x;
  es[tid] = emb[v * EMB + tid];
  __syncthreads();
  const int h = p * 256 + tid;
  float acc = bh[h];
  for (int e = 0; e < EMB; ++e) acc += es[e] * Wih[e * HID + h];
  proj[v * HID + h] = acc;
}

// ---------------- K2: persistent recurrence + inline logits ----------------
// LDS: w_lds 65536 | h_lds 66048 (32 rows x 2064B) | p_lds 8192 | xs 128
__global__ __launch_bounds__(256, 1) void k_rnn(
    const int* __restrict__ x, const float* __restrict__ Whh,
    const float* __restrict__ proj, const float* __restrict__ Who,
    const float* __restrict__ bo, unsigned short* __restrict__ ring,
    float* __restrict__ out, float* __restrict__ final_out,
    unsigned int* __restrict__ flags) {
  extern __shared__ char smem[];
  unsigned short* w_lds = (unsigned short*)smem;            // 65536
  char*           h_lds = smem + 65536;                     // 66048
  float*          p_lds = (float*)(smem + 131584);          // 8192
  int*            xs    = (int*)(smem + 139776);            // 128

  const int tid = threadIdx.x, bid = blockIdx.x;
  const int gi = bid & 7, gj = bid >> 3;                    // group / col-slice
  const int row0 = gi * 32;
  const int lane = tid & 63, wv = tid >> 6;
  const int mt = wv & 1, nt = wv >> 1;                      // recurrence tiles
  const int l15 = lane & 15, q = lane >> 4;

  // W_hh column slice -> LDS bf16 B-fragment order (once).
  for (int it = 0; it < 128; ++it) {
    int u = it * 256 + tid;
    int n = u & 31, j8 = (u >> 5) & 7, qq = (u >> 8) & 3, kb = u >> 10;
    w_lds[((kb * 4 + qq) * 32 + n) * 8 + j8] =
        f2bf(Whh[(kb * 32 + qq * 8 + j8) * HID + gj * 32 + n]);
  }
  // proj slice [64 vocab][32 cols] -> LDS f32 (once).
  for (int it = 0; it < 8; ++it) {
    int u = it * 256 + tid;
    p_lds[u] = proj[(u >> 5) * HID + gj * 32 + (u & 31)];
  }
  if (tid < 32) xs[tid] = x[(row0 + tid) * SEQ];
  // W_ho B-fragments for this wave's 16-voc tile (compiler may rematerialize).
  short8 wf[32];
  #pragma unroll
  for (int kb = 0; kb < 32; ++kb) {
    short8 v8;
    #pragma unroll
    for (int j = 0; j < 8; ++j)
      v8[j] = (short)f2bf(Who[(kb * 32 + q * 8 + j) * VOC + wv * 16 + l15]);
    wf[kb] = v8;
  }
  __syncthreads();

  // flag layout: group gi's producer p -> flags[(gi*32 + p)*32] (128B apart)
  unsigned* flags_g = flags + gi * 32 * 32;
  unsigned* myflag  = flags_g + gj * 32;
  unsigned* rsflag  = flags_g + (tid >> 3) * 32;   // restage producer's flag
  unsigned* laflag  = flags_g + (tid & 31) * 32;   // logits wait-all flag

  const int hcol = gj * 32 + nt * 16 + l15;
  const char* abase = h_lds + (mt * 16 + l15) * 2064 + q * 16;
  const char* bbase = (const char*)w_lds + (q * 32 + nt * 16 + l15) * 16;
  const float bias = bo[wv * 16 + l15];

  for (int t = 0; t < SEQ; ++t) {
    // 1) recurrence MFMA: 32x32 tile = h_prev(32x1024) @ Whh_slice(1024x32)
    f32x4 a0 = {0.f, 0.f, 0.f, 0.f}, a1 = {0.f, 0.f, 0.f, 0.f};
    if (t > 0) {
      #pragma unroll 4
      for (int kb = 0; kb < 32; kb += 2) {
        short8 af0 = *(const short8*)(abase + kb * 64);
        short8 bf0 = *(const short8*)(bbase + kb * 2048);
        a0 = __builtin_amdgcn_mfma_f32_16x16x32_bf16(af0, bf0, a0, 0, 0, 0);
        short8 af1 = *(const short8*)(abase + kb * 64 + 64);
        short8 bf1 = *(const short8*)(bbase + kb * 2048 + 2048);
        a1 = __builtin_amdgcn_mfma_f32_16x16x32_bf16(af1, bf1, a1, 0, 0, 0);
      }
    }
    // 2) epilogue: h_t = tanh(proj[x_t] + acc); publish packed col-pairs.
    unsigned short* slot = ring + (size_t)(t & (RING_SLOTS - 1)) * (BATCH * HID);
    float hv[4];
    #pragma unroll
    for (int r = 0; r < 4; ++r) {
      int ml = mt * 16 + q * 4 + r;                         // D row = q*4+r
      hv[r] = tanhf(p_lds[xs[ml] * 32 + nt * 16 + l15] + a0[r] + a1[r]);
      if (t == SEQ - 1) final_out[(row0 + ml) * HID + hcol] = hv[r];
    }
    #pragma unroll
    for (int r = 0; r < 4; ++r) {
      unsigned myb = f2bf(hv[r]);
      unsigned oth = (unsigned)__shfl_xor((int)myb, 1);
      if ((l15 & 1) == 0) {
        int b = row0 + mt * 16 + q * 4 + r;
        cstore32(slot + (size_t)b * HID + hcol, myb | (oth << 16));
      }
    }
    // 3) release: drain all waves' stores (vmcnt(0) in syncthreads), then
    //    set this producer's flag — its own 128B line, no serialization.
    __syncthreads();
    if (tid == 0)
      __hip_atomic_store(myflag, (unsigned)(t + 1), __ATOMIC_RELAXED,
                         __HIP_MEMORY_SCOPE_AGENT);
    // 4) chunked logits every 16 steps: this block does 16 rows x 1 t x 64 v
    if ((t & 15) == 15) {
      int tsel  = (t - 15) + (gj >> 1);
      // slot tsel must be fully published (binding only when tsel == t;
      // older slots are guaranteed by the skew bound: any block at step t
      // implies every producer finished step t-1).
      wait_flag(laflag, (unsigned)(tsel + 1));
      __syncthreads();
      int rbase = row0 + (gj & 1) * 16;
      const unsigned short* hs =
          ring + (size_t)(tsel & (RING_SLOTS - 1)) * (BATCH * HID) +
          (size_t)(rbase + l15) * HID;                      // A row base
      f32x4 lc = {0.f, 0.f, 0.f, 0.f};
      for (int g = 0; g < 4; ++g) {
        u64 hb[16];
        #pragma unroll
        for (int j = 0; j < 8; ++j) {
          const unsigned short* pk = hs + (g * 8 + j) * 32 + q * 8;
          hb[2 * j]     = cload64(pk);
          hb[2 * j + 1] = cload64(pk + 4);
        }
        #pragma unroll
        for (int j = 0; j < 8; ++j) {
          union { u64 d[2]; short8 s; } c;
          c.d[0] = hb[2 * j]; c.d[1] = hb[2 * j + 1];
          lc = __builtin_amdgcn_mfma_f32_16x16x32_bf16(c.s, wf[g * 8 + j],
                                                       lc, 0, 0, 0);
        }
      }
      #pragma unroll
      for (int rr = 0; rr < 4; ++rr) {
        int b = rbase + q * 4 + rr;
        out[((size_t)b * SEQ + tsel) * VOC + wv * 16 + l15] = lc[rr] + bias;
      }
      // no reuse hazard: 32-slot ring, logits lag <= 15 steps
    }
    // 5) restage h_t (32 rows x 1024) -> h_lds, producer-granular:
    //    thread tid reads cols tid*4..+3 == producer tid>>3's chunk only.
    if (t < SEQ - 1) {
      wait_flag(rsflag, (unsigned)(t + 1));
      u64 tmp[32];
      const unsigned short* base = slot + (size_t)row0 * HID + tid * 4;
      #pragma unroll
      for (int rr = 0; rr < 32; ++rr)
        tmp[rr] = cload64(base + (size_t)rr * HID);
      #pragma unroll
      for (int rr = 0; rr < 32; ++rr)
        *(u64*)(h_lds + rr * 2064 + tid * 8) = tmp[rr];
      if (tid < 32) xs[tid] = x[(row0 + tid) * SEQ + (t + 1)];
      __syncthreads();
    }
  }
}

// ---------------- launch ----------------------------------------------------
extern "C" void kernel_launch(void* const* d_in, const int* in_sizes, int n_in,
                              void* d_out, int out_size, void* d_ws, size_t ws_size,
                              hipStream_t stream) {
  const int*   x   = (const int*)d_in[0];
  const float* emb = (const float*)d_in[1];
  const float* Wih = (const float*)d_in[2];
  const float* Whh = (const float*)d_in[3];
  const float* bh  = (const float*)d_in[4];
  const float* Who = (const float*)d_in[5];
  const float* bo  = (const float*)d_in[6];
  float* out = (float*)d_out;

  char* ws = (char*)d_ws;
  float*          proj  = (float*)ws;                        // 262144 B
  unsigned int*   flags = (unsigned int*)(ws + 262144);      // 32768 B
  unsigned short* ring  = (unsigned short*)(ws + (1 << 20)); // 16 MiB

  size_t need = (size_t)(1 << 20) + (size_t)RING_SLOTS * BATCH * HID * 2;
  if (ws_size < need) return;  // diagnostic fail (absmax) instead of a fault

  (void)hipFuncSetAttribute(reinterpret_cast<const void*>(k_rnn),
                            hipFuncAttributeMaxDynamicSharedMemorySize, 139904);

  k_prep<<<256, 256, 0, stream>>>(emb, Wih, bh, proj);
  hipMemsetAsync(flags, 0, 32768, stream);
  k_rnn<<<256, 256, 139904, stream>>>(x, Whh, proj, Who, bo, ring,
                                      out, out + FINAL_OFF, flags);
}